// Round 8
// baseline (365.379 us; speedup 1.0000x reference)
//
#include <hip/hip_runtime.h>
#include <math.h>

#define BN_EPS 1e-5f
#define STAT_NB 64
#define GBIN 512           // blocks in binning passes
#define BSH 7              // nodes-per-bucket shift (128)

typedef unsigned short u16;
typedef __attribute__((ext_vector_type(8))) unsigned short u16x8;
typedef __attribute__((ext_vector_type(8))) short bf16x8;
typedef __attribute__((ext_vector_type(4))) float f32x4;

__device__ __forceinline__ float bf2f(u16 b){
  union{unsigned int u; float f;} c; c.u = ((unsigned int)b)<<16; return c.f;
}
__device__ __forceinline__ u16 f2bf(float f){
  union{float f; unsigned int u;} c; c.f=f;
  unsigned int u = c.u;
  return (u16)((u + 0x7fffu + ((u>>16)&1u)) >> 16);
}

// ---------------- prep: all dtype conversions + flag zeroing, one launch ----
// blocks 0..31: Wb1 = [Wl|Wr] cat (8192x8 elems)
// blocks 32..63: Wb2 = W1 (8192x8)
// blocks 64..71: Wb3 = W2 (2048x8)
// blocks 72.. : x fp32 -> Acat[:,128:256] bf16 (grid-stride)
__global__ __launch_bounds__(256) void k_prep(
    const float* __restrict__ Wl, const float* __restrict__ Wr,
    const float* __restrict__ W1, const float* __restrict__ W2,
    const float* __restrict__ x,
    u16* __restrict__ Wb1, u16* __restrict__ Wb2, u16* __restrict__ Wb3,
    u16* __restrict__ Acat, int n, int* __restrict__ flags){
  int bid = blockIdx.x, tid = threadIdx.x;
  if (bid==0 && tid<8) flags[tid]=0;
  auto cv8 = [](const float* s)->u16x8{
    float4 a = ((const float4*)s)[0], b = ((const float4*)s)[1];
    u16x8 v;
    v[0]=f2bf(a.x); v[1]=f2bf(a.y); v[2]=f2bf(a.z); v[3]=f2bf(a.w);
    v[4]=f2bf(b.x); v[5]=f2bf(b.y); v[6]=f2bf(b.z); v[7]=f2bf(b.w);
    return v;
  };
  if (bid < 32){
    int i = bid*256 + tid;              // 8192
    int c = i>>5, kb = (i&31)*8;
    const float* src = (kb<128) ? (Wl + (size_t)c*128 + kb) : (Wr + (size_t)c*128 + kb-128);
    *(u16x8*)(Wb1 + (size_t)c*256 + kb) = cv8(src);
  } else if (bid < 64){
    int i = (bid-32)*256 + tid;         // 8192
    *(u16x8*)(Wb2 + (size_t)i*8) = cv8(W1 + (size_t)i*8);
  } else if (bid < 72){
    int i = (bid-64)*256 + tid;         // 2048
    if (i < 2048) *(u16x8*)(Wb3 + (size_t)i*8) = cv8(W2 + (size_t)i*8);
  } else {
    int i = (bid-72)*256 + tid;
    int total = n*16;
    int stride = (gridDim.x-72)*256;
    for (; i<total; i+=stride){
      int r = i>>4, kb = (i&15)*8;
      *(u16x8*)(Acat + (size_t)r*256 + 128 + kb) = cv8(x + (size_t)r*128 + kb);
    }
  }
}

// ---------------- CSR build via radix partition ----------------
// layout: blkhist[blk*nbkt + b]  (coalesced writes in hist, lane-coalesced rowscan)

__global__ __launch_bounds__(256) void k_hist(const int* __restrict__ ei, int E, int nbkt,
                                              int* __restrict__ blkhist){
  __shared__ int hist[1024];
  int tid = threadIdx.x, blk = blockIdx.x;
  for (int b=tid;b<1024;b+=256) hist[b]=0;
  __syncthreads();
  int per = (E + GBIN - 1)/GBIN;
  int e0 = blk*per, e1 = min(E, e0+per);
  for (int e=e0+tid; e<e1; e+=256)
    atomicAdd(&hist[ei[(size_t)E+e]>>BSH], 1);
  __syncthreads();
  for (int b=tid;b<nbkt;b+=256) blkhist[(size_t)blk*nbkt + b] = hist[b];
}

// per-bucket exclusive prefix over GBIN block counts (lane-coalesced)
__global__ void k_rowscan(int* __restrict__ blkhist, int nbkt, int* __restrict__ bbase){
  int b = blockIdx.x*blockDim.x + threadIdx.x;
  if (b >= nbkt) return;
  int run = 0;
  for (int k=0;k<GBIN;k++){
    size_t idx = (size_t)k*nbkt + b;
    int t = blkhist[idx];
    blkhist[idx] = run;
    run += t;
  }
  bbase[b] = run;
}

// exclusive scan of bucket totals (single block), sentinel bbase[nbkt]=E
__global__ void k_bscan(int* __restrict__ bbase, int nbkt){
  __shared__ int s[1024];
  int tid = threadIdx.x;
  int v = (tid<nbkt)? bbase[tid] : 0;
  s[tid]=v; __syncthreads();
  #pragma unroll
  for (int o=1;o<1024;o<<=1){
    int t = (tid>=o)? s[tid-o] : 0;
    __syncthreads();
    s[tid]+=t;
    __syncthreads();
  }
  if (tid<nbkt) bbase[tid] = s[tid]-v;
  if (tid==1023) bbase[nbkt] = s[1023];
}

// scatter packed pairs (src<<BSH | dst&127) into per-(block,bucket) ranges
__global__ __launch_bounds__(256) void k_scatter(const int* __restrict__ ei, int E, int nbkt,
                                                 const int* __restrict__ blkhist,
                                                 const int* __restrict__ bbase,
                                                 int* __restrict__ pairs){
  __shared__ int cur[1024];
  int tid = threadIdx.x, blk = blockIdx.x;
  for (int b=tid;b<nbkt;b+=256) cur[b] = bbase[b] + blkhist[(size_t)blk*nbkt + b];
  __syncthreads();
  int per = (E + GBIN - 1)/GBIN;
  int e0 = blk*per, e1 = min(E, e0+per);
  for (int e=e0+tid; e<e1; e+=256){
    int dst = ei[(size_t)E+e];
    int src = ei[e];
    int b = dst>>BSH;
    int p = atomicAdd(&cur[b], 1);
    pairs[p] = (src<<BSH) | (dst & 127);
  }
}

// one block per bucket: counting-sort pairs -> eidx, emit deg/off directly
__global__ __launch_bounds__(256) void k_bucket_csr(const int* __restrict__ pairs,
                                                    const int* __restrict__ bbase,
                                                    int nbkt, int n,
                                                    int* __restrict__ deg, int* __restrict__ off,
                                                    int* __restrict__ eidx){
  __shared__ int hist[128], loff[128], cur2[128];
  int tid = threadIdx.x, b = blockIdx.x;
  if (b >= nbkt) return;
  int n0 = b<<BSH;
  int nn = min(128, n - n0);
  int e0 = bbase[b], e1 = bbase[b+1];
  int cnt = e1 - e0;
  if (tid<128) hist[tid]=0;
  __syncthreads();
  for (int i=tid;i<cnt;i+=256)
    atomicAdd(&hist[pairs[e0+i] & 127], 1);
  __syncthreads();
  int hv=0;
  if (tid<128){ hv = hist[tid]; loff[tid] = hv; }
  __syncthreads();
  #pragma unroll
  for (int o=1;o<128;o<<=1){
    int t = (tid<128 && tid>=o)? loff[tid-o] : 0;
    __syncthreads();
    if (tid<128) loff[tid]+=t;
    __syncthreads();
  }
  if (tid<128){
    int ex = loff[tid]-hv;
    cur2[tid] = ex;
    if (tid<nn){
      deg[n0+tid] = hv;
      off[n0+tid] = e0 + ex;
    }
  }
  __syncthreads();
  for (int i=tid;i<cnt;i+=256){
    int v = pairs[e0+i];
    int p = atomicAdd(&cur2[v & 127], 1);
    eidx[e0 + p] = v>>BSH;
  }
}

// one wave per node, 8 edge-slots x 8 lanes: mean of bf16 rows
__global__ void k_aggregate(u16* Acat, const int* __restrict__ off,
                            const int* __restrict__ deg, const int* __restrict__ eidx, int n){
  int wid = (blockIdx.x*blockDim.x + threadIdx.x) >> 6;
  int lane = threadIdx.x & 63;
  if (wid >= n) return;
  int o = off[wid], d = deg[wid];
  int eslot = lane >> 3;        // 0..7
  int ck = (lane & 7) * 16;     // 16 channels (32B) per lane
  float f[16];
  #pragma unroll
  for (int j=0;j<16;j++) f[j]=0.f;
  #pragma unroll 2
  for (int i = eslot; i < d; i += 8){
    int s = eidx[o+i];
    const u16x8* src = (const u16x8*)(Acat + (size_t)s*256 + 128 + ck);
    u16x8 v0 = src[0], v1 = src[1];
    #pragma unroll
    for (int j=0;j<8;j++) f[j]   += bf2f(v0[j]);
    #pragma unroll
    for (int j=0;j<8;j++) f[8+j] += bf2f(v1[j]);
  }
  #pragma unroll
  for (int j=0;j<16;j++){
    f[j] += __shfl_xor(f[j], 8, 64);
    f[j] += __shfl_xor(f[j], 16, 64);
    f[j] += __shfl_xor(f[j], 32, 64);
  }
  if (lane < 8){
    float inv = 1.f/(float)max(d,1);
    u16x8 r0, r1;
    #pragma unroll
    for (int j=0;j<8;j++){ r0[j]=f2bf(f[j]*inv); r1[j]=f2bf(f[8+j]*inv); }
    u16x8* dst = (u16x8*)(Acat + (size_t)wid*256 + ck);
    dst[0]=r0; dst[1]=r1;
  }
}

// ---------------- bf16 MFMA GEMM ----------------
// out[r][c] = sum_k relu?(bn?(A[r][k])) * W[c][k] + bias[c], K=256 fixed
// tile 128 x COLS (COLS=256: single column block, A read once), 4 waves 2x2,
// BK=64, XOR-swizzled LDS.

template<int COLS>
__global__ __launch_bounds__(256, 2) void k_gemm_mfma(
    const u16* __restrict__ A, const u16* __restrict__ W,
    const float* __restrict__ ss, int has_ss,
    const float* __restrict__ bias, u16* __restrict__ out,
    int nrows, int hout,
    float* __restrict__ psum, float* __restrict__ psq)
{
  constexpr int WN  = COLS/2;   // per-wave cols
  constexpr int NFR = WN/16;    // n-fragments per wave
  __shared__ u16 As[128*64];
  __shared__ u16 Bs[COLS*64];
  __shared__ float scs[256], shs[256];
  __shared__ float red[2][2][COLS];

  int tid  = threadIdx.x;
  int lane = tid & 63, wave = tid >> 6;
  int wr = wave >> 1, wc = wave & 1;
  int rbase = blockIdx.x*128;
  constexpr int cbase = 0;

  if (has_ss){ scs[tid] = ss[tid]; shs[tid] = ss[256+tid]; }
  __syncthreads();

  f32x4 acc[4][NFR];
  #pragma unroll
  for (int m=0;m<4;m++)
    #pragma unroll
    for (int n=0;n<NFR;n++)
      acc[m][n] = (f32x4){0.f,0.f,0.f,0.f};

  // A staging: thread -> (row, 32-col half); 4 x u16x8 per K-tile
  int arow = tid >> 1;
  int acb  = (tid & 1) * 32;
  bool avalid = (rbase + arow) < nrows;
  const u16* aptr = A + (size_t)(rbase+arow)*256 + acb;
  // B staging
  int brow, bcb;
  if (COLS==256)      { brow = tid;    bcb = 0; }
  else if (COLS==128) { brow = tid>>1; bcb = (tid&1)*32; }
  else                { brow = tid>>2; bcb = (tid&3)*16; }
  const u16* bptr = W + (size_t)(cbase+brow)*256 + bcb;

  for (int kt=0; kt<256; kt+=64){
    #pragma unroll
    for (int q=0;q<4;q++){
      u16x8 v = (u16x8){0,0,0,0,0,0,0,0};
      if (avalid) v = *(const u16x8*)(aptr + kt + q*8);
      if (has_ss){
        int k = acb + q*8;
        #pragma unroll
        for (int e=0;e<8;e++){
          float f = bf2f(v[e]);
          f = fmaxf(fmaf(f, scs[kt+k+e], shs[kt+k+e]), 0.f);
          v[e] = f2bf(f);
        }
      }
      int slot = ((acb>>3) + q) ^ (arow & 7);
      *(u16x8*)(As + arow*64 + slot*8) = v;
    }
    #pragma unroll
    for (int q=0;q<(COLS==256?8:COLS/32);q++){
      u16x8 v = *(const u16x8*)(bptr + kt + q*8);
      int slot = ((bcb>>3) + q) ^ (brow & 7);
      *(u16x8*)(Bs + brow*64 + slot*8) = v;
    }
    __syncthreads();

    int fr = lane & 15, g = lane >> 4;
    #pragma unroll
    for (int kk=0;kk<2;kk++){
      bf16x8 af[4], bfr[NFR];
      #pragma unroll
      for (int m=0;m<4;m++){
        int row = wr*64 + m*16 + fr;
        int slot = (kk*4 + g) ^ (row & 7);
        af[m] = *(const bf16x8*)(As + row*64 + slot*8);
      }
      #pragma unroll
      for (int n=0;n<NFR;n++){
        int row = wc*WN + n*16 + fr;
        int slot = (kk*4 + g) ^ (row & 7);
        bfr[n] = *(const bf16x8*)(Bs + row*64 + slot*8);
      }
      #pragma unroll
      for (int m=0;m<4;m++)
        #pragma unroll
        for (int n=0;n<NFR;n++)
          acc[m][n] = __builtin_amdgcn_mfma_f32_16x16x32_bf16(af[m], bfr[n], acc[m][n], 0, 0, 0);
    }
    __syncthreads();
  }

  // epilogue: bias, bf16 store, BN partial stats
  int cl = lane & 15, g = lane >> 4;
  float bv[NFR], sn[NFR], qn[NFR];
  #pragma unroll
  for (int n=0;n<NFR;n++){
    bv[n] = bias[cbase + wc*WN + n*16 + cl];
    sn[n] = 0.f; qn[n] = 0.f;
  }
  #pragma unroll
  for (int m=0;m<4;m++){
    int r0 = rbase + wr*64 + m*16 + g*4;
    #pragma unroll
    for (int n=0;n<NFR;n++){
      int c = cbase + wc*WN + n*16 + cl;
      #pragma unroll
      for (int i=0;i<4;i++){
        int r = r0 + i;
        if (r < nrows){
          float v = acc[m][n][i] + bv[n];
          out[(size_t)r*hout + c] = f2bf(v);
          sn[n] += v; qn[n] += v*v;
        }
      }
    }
  }
  #pragma unroll
  for (int n=0;n<NFR;n++){
    sn[n] += __shfl_xor(sn[n], 16, 64);
    sn[n] += __shfl_xor(sn[n], 32, 64);
    qn[n] += __shfl_xor(qn[n], 16, 64);
    qn[n] += __shfl_xor(qn[n], 32, 64);
  }
  if (lane < 16){
    #pragma unroll
    for (int n=0;n<NFR;n++){
      int cc = wc*WN + n*16 + lane;
      red[0][wr][cc] = sn[n];
      red[1][wr][cc] = qn[n];
    }
  }
  __syncthreads();
  if (tid < COLS){
    psum[(size_t)blockIdx.x*hout + cbase + tid] = red[0][0][tid] + red[0][1][tid];
    psq [(size_t)blockIdx.x*hout + cbase + tid] = red[1][0][tid] + red[1][1][tid];
  }
}

// ---- stats: partial fold + last-block final fold (deterministic: fixed order sums) ----
__global__ __launch_bounds__(256) void k_stats_partfold(
    const float* __restrict__ psum, const float* __restrict__ psq,
    int rt, int h, float* __restrict__ part, float ninv,
    const float* __restrict__ g, const float* __restrict__ b_,
    float* __restrict__ ss, int* __restrict__ counter){
  __shared__ int isLast;
  int c = threadIdx.x, b = blockIdx.x;
  int chunk = (rt + STAT_NB - 1)/STAT_NB;
  int i0 = b*chunk;
  int i1 = min(rt, i0+chunk);
  if (c < h){
    float s0=0.f,s1=0.f,s2=0.f,s3=0.f, q0=0.f,q1=0.f,q2=0.f,q3=0.f;
    int i=i0;
    for (; i+3<i1; i+=4){
      s0 += psum[(size_t)i*h+c];     q0 += psq[(size_t)i*h+c];
      s1 += psum[(size_t)(i+1)*h+c]; q1 += psq[(size_t)(i+1)*h+c];
      s2 += psum[(size_t)(i+2)*h+c]; q2 += psq[(size_t)(i+2)*h+c];
      s3 += psum[(size_t)(i+3)*h+c]; q3 += psq[(size_t)(i+3)*h+c];
    }
    for (; i<i1; ++i){ s0 += psum[(size_t)i*h+c]; q0 += psq[(size_t)i*h+c]; }
    part[((size_t)b*2  )*h + c] = (s0+s1)+(s2+s3);
    part[((size_t)b*2+1)*h + c] = (q0+q1)+(q2+q3);
  }
  __threadfence();
  if (c==0) isLast = (atomicAdd(counter,1) == gridDim.x-1);
  __syncthreads();
  if (isLast && c < h){
    float S0=0.f,S1=0.f,Q0=0.f,Q1=0.f;
    #pragma unroll 2
    for (int b2=0;b2<STAT_NB;b2+=2){
      S0 += part[((size_t)b2*2  )*h + c];
      Q0 += part[((size_t)b2*2+1)*h + c];
      S1 += part[((size_t)(b2+1)*2  )*h + c];
      Q1 += part[((size_t)(b2+1)*2+1)*h + c];
    }
    float S = S0+S1, Q = Q0+Q1;
    float m = S*ninv;
    float v = fmaxf(Q*ninv - m*m, 0.f);
    float sc = g[c] * rsqrtf(v + BN_EPS);
    ss[c]   = sc;
    ss[h+c] = b_[c] - m*sc;
  }
}

// 64 -> 14 linear (bf16 input, weights in LDS), fused BN+relu, emits stats
__global__ __launch_bounds__(256) void k_lin3(const u16* __restrict__ h3, const float* __restrict__ ss3,
     const float* __restrict__ W3, const float* __restrict__ b3,
     float* __restrict__ h4, int n, float* __restrict__ psum, float* __restrict__ psq){
  __shared__ float Ws[14*64];
  __shared__ float bs[14];
  __shared__ float sc[64], sh[64];
  __shared__ float redp[2][14][4];
  int tid=threadIdx.x;
  for (int i=tid;i<896;i+=256) Ws[i]=W3[i];
  if (tid<14) bs[tid]=b3[tid];
  if (tid<64){ sc[tid]=ss3[tid]; sh[tid]=ss3[64+tid]; }
  __syncthreads();
  int node = blockIdx.x*256 + tid;
  float o[14];
  #pragma unroll
  for (int hh=0;hh<14;hh++) o[hh]=0.f;
  if (node<n){
    const u16x8* ar = (const u16x8*)(h3 + (size_t)node*64);
    #pragma unroll
    for (int kv=0;kv<8;kv++){
      u16x8 v = ar[kv];
      #pragma unroll
      for (int j=0;j<8;j++){
        int k=kv*8+j;
        float a = fmaxf(fmaf(bf2f(v[j]), sc[k], sh[k]), 0.f);
        #pragma unroll
        for (int hh=0;hh<14;hh++) o[hh] = fmaf(a, Ws[hh*64+k], o[hh]);
      }
    }
    #pragma unroll
    for (int hh=0;hh<14;hh++){ o[hh]+=bs[hh]; h4[(size_t)node*14+hh]=o[hh]; }
  }
  int lane = tid & 63, w = tid>>6;
  #pragma unroll
  for (int hh=0;hh<14;hh++){
    float sv = (node<n)? o[hh] : 0.f;
    float qv = sv*sv;
    #pragma unroll
    for (int offs=32;offs>0;offs>>=1){
      sv += __shfl_down(sv,offs,64);
      qv += __shfl_down(qv,offs,64);
    }
    if (lane==0){ redp[0][hh][w]=sv; redp[1][hh][w]=qv; }
  }
  __syncthreads();
  if (tid<14){
    float t=redp[0][tid][0]+redp[0][tid][1]+redp[0][tid][2]+redp[0][tid][3];
    psum[(size_t)blockIdx.x*14+tid]=t;
  } else if (tid>=64 && tid<78){
    int c=tid-64;
    float t=redp[1][c][0]+redp[1][c][1]+redp[1][c][2]+redp[1][c][3];
    psq[(size_t)blockIdx.x*14+c]=t;
  }
}

// 14 -> 2 + log_softmax
__global__ void k_final(const float* __restrict__ h4, const float* __restrict__ ss4,
   const float* __restrict__ W4, const float* __restrict__ b4, float* __restrict__ out, int n){
  int node = blockIdx.x*blockDim.x+threadIdx.x;
  if (node>=n) return;
  float z0=b4[0], z1=b4[1];
  #pragma unroll
  for (int j=0;j<14;j++){
    float a = fmaxf(h4[(size_t)node*14+j]*ss4[j]+ss4[14+j], 0.f);
    z0 = fmaf(a, W4[j],    z0);
    z1 = fmaf(a, W4[14+j], z1);
  }
  float m = fmaxf(z0,z1);
  float lse = m + logf(expf(z0-m)+expf(z1-m));
  out[(size_t)node*2]   = z0-lse;
  out[(size_t)node*2+1] = z1-lse;
}

extern "C" void kernel_launch(void* const* d_in, const int* in_sizes, int n_in,
                              void* d_out, int out_size, void* d_ws, size_t ws_size,
                              hipStream_t stream){
  const float* x    = (const float*)d_in[0];
  const int*   ei   = (const int*)d_in[1];          // int64 in ref -> int32 on device per harness
  const float* Wl   = (const float*)d_in[2];
  const float* bl   = (const float*)d_in[3];
  const float* Wr   = (const float*)d_in[4];
  const float* bn_g = (const float*)d_in[5];
  const float* bn_b = (const float*)d_in[6];
  const float* W1   = (const float*)d_in[7];
  const float* b1   = (const float*)d_in[8];
  const float* W2   = (const float*)d_in[9];
  const float* b2   = (const float*)d_in[10];
  const float* W3   = (const float*)d_in[11];
  const float* b3   = (const float*)d_in[12];
  const float* W4   = (const float*)d_in[13];
  const float* b4   = (const float*)d_in[14];
  const float* g1   = (const float*)d_in[15];
  const float* bb1  = (const float*)d_in[16];
  const float* g2   = (const float*)d_in[17];
  const float* bb2  = (const float*)d_in[18];
  const float* g3   = (const float*)d_in[19];
  const float* bb3  = (const float*)d_in[20];

  const int N = in_sizes[0]/128;
  const int E = in_sizes[1]/2;
  const int NBKT = (N + 127) >> BSH;     // 128 nodes per bucket
  const int RT2 = (N+127)/128;   // 128-row GEMM tiles
  const int RT4 = (N+255)/256;   // lin3 blocks

  char* p = (char*)d_ws;
  auto alloc = [&](size_t bytes)->void*{
    void* r = (void*)p;
    p += (bytes + 255) & ~(size_t)255;
    return r;
  };
  int* deg      = (int*)alloc((size_t)N*sizeof(int));
  int* off      = (int*)alloc((size_t)N*sizeof(int));
  int* bbase    = (int*)alloc(1025*sizeof(int));
  int* flags    = (int*)alloc(16*sizeof(int));
  int* blkhist  = (int*)alloc((size_t)1024*GBIN*sizeof(int));
  int* pairs    = (int*)alloc((size_t)E*sizeof(int));
  int* eidx     = (int*)alloc((size_t)E*sizeof(int));
  u16* Acat     = (u16*)alloc((size_t)N*256*sizeof(u16));  // [agg | x] bf16; reused as h2
  u16* h1b      = (u16*)alloc((size_t)N*256*sizeof(u16));  // gemm1 out; reused as h3
  float* h4     = (float*)alloc((size_t)N*14*sizeof(float));
  u16* Wb1      = (u16*)alloc(256*256*sizeof(u16));
  u16* Wb2      = (u16*)alloc(256*256*sizeof(u16));
  u16* Wb3      = (u16*)alloc(64*256*sizeof(u16));
  float* psum   = (float*)alloc((size_t)RT2*256*sizeof(float));
  float* psq    = (float*)alloc((size_t)RT2*256*sizeof(float));
  float* part   = (float*)alloc((size_t)STAT_NB*2*256*sizeof(float));
  float* ssb    = (float*)alloc(4*512*sizeof(float));
  u16* h2b = Acat;
  u16* h3b = h1b;
  float* ss1=ssb, *ss2=ssb+512, *ss3=ssb+1024, *ss4=ssb+1536;
  const float ninv = 1.f/(float)N;

  // prep: all conversions + flag zeroing (one launch)
  k_prep<<<dim3(72+2048), dim3(256), 0, stream>>>(Wl, Wr, W1, W2, x, Wb1, Wb2, Wb3, Acat, N, flags);

  // CSR build: histogram -> scans -> partition scatter -> per-bucket sort
  k_hist<<<dim3(GBIN), dim3(256), 0, stream>>>(ei, E, NBKT, blkhist);
  k_rowscan<<<dim3((NBKT+255)/256), dim3(256), 0, stream>>>(blkhist, NBKT, bbase);
  k_bscan<<<dim3(1), dim3(1024), 0, stream>>>(bbase, NBKT);
  k_scatter<<<dim3(GBIN), dim3(256), 0, stream>>>(ei, E, NBKT, blkhist, bbase, pairs);
  k_bucket_csr<<<dim3(NBKT), dim3(256), 0, stream>>>(pairs, bbase, NBKT, N, deg, off, eidx);

  // mean aggregate (bf16 gather, 8-way edge-parallel) -> Acat[:,0:128]
  k_aggregate<<<dim3((N+3)/4), dim3(256), 0, stream>>>(Acat, off, deg, eidx, N);

  // GEMM1: h1 = Acat @ Wb1^T + bl   (K=256 = [agg|x] vs [Wl|Wr])
  k_gemm_mfma<256><<<dim3(RT2), dim3(256), 0, stream>>>(
      Acat, Wb1, (const float*)0, 0, bl, h1b, N, 256, psum, psq);
  k_stats_partfold<<<dim3(STAT_NB), dim3(256), 0, stream>>>(
      psum, psq, RT2, 256, part, ninv, bn_g, bn_b, ss1, flags+0);

  // GEMM2: h2 = relu(bn(h1)) @ W1^T + b1
  k_gemm_mfma<256><<<dim3(RT2), dim3(256), 0, stream>>>(
      h1b, Wb2, ss1, 1, b1, h2b, N, 256, psum, psq);
  k_stats_partfold<<<dim3(STAT_NB), dim3(256), 0, stream>>>(
      psum, psq, RT2, 256, part, ninv, g1, bb1, ss2, flags+1);

  // GEMM3: h3 = relu(bn(h2)) @ W2^T + b2  (hout=64)
  k_gemm_mfma<64><<<dim3(RT2), dim3(256), 0, stream>>>(
      h2b, Wb3, ss2, 1, b2, h3b, N, 64, psum, psq);
  k_stats_partfold<<<dim3(STAT_NB), dim3(256), 0, stream>>>(
      psum, psq, RT2, 64, part, ninv, g2, bb2, ss3, flags+2);

  // h4 = relu(bn(h3)) @ W3^T + b3   (hout=14)
  k_lin3<<<dim3(RT4), dim3(256), 0, stream>>>(h3b, ss3, W3, b3, h4, N, psum, psq);
  k_stats_partfold<<<dim3(STAT_NB), dim3(256), 0, stream>>>(
      psum, psq, RT4, 14, part, ninv, g3, bb3, ss4, flags+3);

  // out = log_softmax(relu(bn(h4)) @ W4^T + b4)
  k_final<<<dim3((N+255)/256), dim3(256), 0, stream>>>(h4, ss4, W4, b4, (float*)d_out, N);
}

// Round 9
// 301.989 us; speedup vs baseline: 1.2099x; 1.2099x over previous
//
#include <hip/hip_runtime.h>
#include <math.h>

#define BN_EPS 1e-5f
#define STAT_NB 64
#define GBIN 512           // blocks in binning passes
#define BSH 7              // nodes-per-bucket shift (128)

typedef unsigned short u16;
typedef __attribute__((ext_vector_type(8))) unsigned short u16x8;
typedef __attribute__((ext_vector_type(8))) short bf16x8;
typedef __attribute__((ext_vector_type(4))) float f32x4;

__device__ __forceinline__ float bf2f(u16 b){
  union{unsigned int u; float f;} c; c.u = ((unsigned int)b)<<16; return c.f;
}
__device__ __forceinline__ u16 f2bf(float f){
  union{float f; unsigned int u;} c; c.f=f;
  unsigned int u = c.u;
  return (u16)((u + 0x7fffu + ((u>>16)&1u)) >> 16);
}

// ---------------- prep: all dtype conversions + flag zeroing, one launch ----
__global__ __launch_bounds__(256) void k_prep(
    const float* __restrict__ Wl, const float* __restrict__ Wr,
    const float* __restrict__ W1, const float* __restrict__ W2,
    const float* __restrict__ x,
    u16* __restrict__ Wb1, u16* __restrict__ Wb2, u16* __restrict__ Wb3,
    u16* __restrict__ Acat, int n, int* __restrict__ flags){
  int bid = blockIdx.x, tid = threadIdx.x;
  if (bid==0 && tid<8) flags[tid]=0;
  auto cv8 = [](const float* s)->u16x8{
    float4 a = ((const float4*)s)[0], b = ((const float4*)s)[1];
    u16x8 v;
    v[0]=f2bf(a.x); v[1]=f2bf(a.y); v[2]=f2bf(a.z); v[3]=f2bf(a.w);
    v[4]=f2bf(b.x); v[5]=f2bf(b.y); v[6]=f2bf(b.z); v[7]=f2bf(b.w);
    return v;
  };
  if (bid < 32){
    int i = bid*256 + tid;              // 8192
    int c = i>>5, kb = (i&31)*8;
    const float* src = (kb<128) ? (Wl + (size_t)c*128 + kb) : (Wr + (size_t)c*128 + kb-128);
    *(u16x8*)(Wb1 + (size_t)c*256 + kb) = cv8(src);
  } else if (bid < 64){
    int i = (bid-32)*256 + tid;         // 8192
    *(u16x8*)(Wb2 + (size_t)i*8) = cv8(W1 + (size_t)i*8);
  } else if (bid < 72){
    int i = (bid-64)*256 + tid;         // 2048
    if (i < 2048) *(u16x8*)(Wb3 + (size_t)i*8) = cv8(W2 + (size_t)i*8);
  } else {
    int i = (bid-72)*256 + tid;
    int total = n*16;
    int stride = (gridDim.x-72)*256;
    for (; i<total; i+=stride){
      int r = i>>4, kb = (i&15)*8;
      *(u16x8*)(Acat + (size_t)r*256 + 128 + kb) = cv8(x + (size_t)r*128 + kb);
    }
  }
}

// ---------------- CSR build via radix partition ----------------
// layout: blkhist[b*GBIN + blk]  (contiguous 2KB row per bucket)

__global__ __launch_bounds__(256) void k_hist(const int* __restrict__ ei, int E, int nbkt,
                                              int* __restrict__ blkhist){
  __shared__ int hist[1024];
  int tid = threadIdx.x, blk = blockIdx.x;
  for (int b=tid;b<1024;b+=256) hist[b]=0;
  __syncthreads();
  int per = (E + GBIN - 1)/GBIN;
  int e0 = blk*per, e1 = min(E, e0+per);
  for (int e=e0+tid; e<e1; e+=256)
    atomicAdd(&hist[ei[(size_t)E+e]>>BSH], 1);
  __syncthreads();
  for (int b=tid;b<nbkt;b+=256) blkhist[(size_t)b*GBIN + blk] = hist[b];
}

// wave-parallel per-bucket exclusive prefix over GBIN block counts (in place).
// one wave per bucket; lane l owns 8 consecutive k (coalesced 2KB row read).
__global__ __launch_bounds__(256) void k_rowscan(int* __restrict__ blkhist, int nbkt,
                                                 int* __restrict__ bbase){
  int wid = (blockIdx.x*blockDim.x + threadIdx.x) >> 6;
  int lane = threadIdx.x & 63;
  if (wid >= nbkt) return;
  int* row = blkhist + (size_t)wid*GBIN + lane*8;
  int v[8];
  #pragma unroll
  for (int j=0;j<8;j++) v[j] = row[j];
  int s = 0;
  #pragma unroll
  for (int j=0;j<8;j++){ int t = v[j]; v[j] = s; s += t; }
  int incl = s;
  #pragma unroll
  for (int o=1;o<64;o<<=1){
    int t = __shfl_up(incl, o, 64);
    if (lane >= o) incl += t;
  }
  int excl = incl - s;
  #pragma unroll
  for (int j=0;j<8;j++) row[j] = v[j] + excl;
  if (lane == 63) bbase[wid] = incl;
}

// exclusive scan of bucket totals (single block), sentinel bbase[nbkt]=E
__global__ void k_bscan(int* __restrict__ bbase, int nbkt){
  __shared__ int s[1024];
  int tid = threadIdx.x;
  int v = (tid<nbkt)? bbase[tid] : 0;
  s[tid]=v; __syncthreads();
  #pragma unroll
  for (int o=1;o<1024;o<<=1){
    int t = (tid>=o)? s[tid-o] : 0;
    __syncthreads();
    s[tid]+=t;
    __syncthreads();
  }
  if (tid<nbkt) bbase[tid] = s[tid]-v;
  if (tid==1023) bbase[nbkt] = s[1023];
}

// scatter packed pairs (src<<BSH | dst&127) into per-(block,bucket) ranges
__global__ __launch_bounds__(256) void k_scatter(const int* __restrict__ ei, int E, int nbkt,
                                                 const int* __restrict__ blkhist,
                                                 const int* __restrict__ bbase,
                                                 int* __restrict__ pairs){
  __shared__ int cur[1024];
  int tid = threadIdx.x, blk = blockIdx.x;
  for (int b=tid;b<nbkt;b+=256) cur[b] = bbase[b] + blkhist[(size_t)b*GBIN + blk];
  __syncthreads();
  int per = (E + GBIN - 1)/GBIN;
  int e0 = blk*per, e1 = min(E, e0+per);
  for (int e=e0+tid; e<e1; e+=256){
    int dst = ei[(size_t)E+e];
    int src = ei[e];
    int b = dst>>BSH;
    int p = atomicAdd(&cur[b], 1);
    pairs[p] = (src<<BSH) | (dst & 127);
  }
}

// one block per bucket: counting-sort pairs -> eidx, emit deg/off directly
__global__ __launch_bounds__(256) void k_bucket_csr(const int* __restrict__ pairs,
                                                    const int* __restrict__ bbase,
                                                    int nbkt, int n,
                                                    int* __restrict__ deg, int* __restrict__ off,
                                                    int* __restrict__ eidx){
  __shared__ int hist[128], loff[128], cur2[128];
  int tid = threadIdx.x, b = blockIdx.x;
  if (b >= nbkt) return;
  int n0 = b<<BSH;
  int nn = min(128, n - n0);
  int e0 = bbase[b], e1 = bbase[b+1];
  int cnt = e1 - e0;
  if (tid<128) hist[tid]=0;
  __syncthreads();
  for (int i=tid;i<cnt;i+=256)
    atomicAdd(&hist[pairs[e0+i] & 127], 1);
  __syncthreads();
  int hv=0;
  if (tid<128){ hv = hist[tid]; loff[tid] = hv; }
  __syncthreads();
  #pragma unroll
  for (int o=1;o<128;o<<=1){
    int t = (tid<128 && tid>=o)? loff[tid-o] : 0;
    __syncthreads();
    if (tid<128) loff[tid]+=t;
    __syncthreads();
  }
  if (tid<128){
    int ex = loff[tid]-hv;
    cur2[tid] = ex;
    if (tid<nn){
      deg[n0+tid] = hv;
      off[n0+tid] = e0 + ex;
    }
  }
  __syncthreads();
  for (int i=tid;i<cnt;i+=256){
    int v = pairs[e0+i];
    int p = atomicAdd(&cur2[v & 127], 1);
    eidx[e0 + p] = v>>BSH;
  }
}

// one wave per node, 8 edge-slots x 8 lanes: mean of bf16 rows
__global__ void k_aggregate(u16* Acat, const int* __restrict__ off,
                            const int* __restrict__ deg, const int* __restrict__ eidx, int n){
  int wid = (blockIdx.x*blockDim.x + threadIdx.x) >> 6;
  int lane = threadIdx.x & 63;
  if (wid >= n) return;
  int o = off[wid], d = deg[wid];
  int eslot = lane >> 3;        // 0..7
  int ck = (lane & 7) * 16;     // 16 channels (32B) per lane
  float f[16];
  #pragma unroll
  for (int j=0;j<16;j++) f[j]=0.f;
  #pragma unroll 2
  for (int i = eslot; i < d; i += 8){
    int s = eidx[o+i];
    const u16x8* src = (const u16x8*)(Acat + (size_t)s*256 + 128 + ck);
    u16x8 v0 = src[0], v1 = src[1];
    #pragma unroll
    for (int j=0;j<8;j++) f[j]   += bf2f(v0[j]);
    #pragma unroll
    for (int j=0;j<8;j++) f[8+j] += bf2f(v1[j]);
  }
  #pragma unroll
  for (int j=0;j<16;j++){
    f[j] += __shfl_xor(f[j], 8, 64);
    f[j] += __shfl_xor(f[j], 16, 64);
    f[j] += __shfl_xor(f[j], 32, 64);
  }
  if (lane < 8){
    float inv = 1.f/(float)max(d,1);
    u16x8 r0, r1;
    #pragma unroll
    for (int j=0;j<8;j++){ r0[j]=f2bf(f[j]*inv); r1[j]=f2bf(f[8+j]*inv); }
    u16x8* dst = (u16x8*)(Acat + (size_t)wid*256 + ck);
    dst[0]=r0; dst[1]=r1;
  }
}

// ---------------- bf16 MFMA GEMM ----------------
// tile 128 x COLS (COLS=256: single column block, A read once), 4 waves 2x2,
// BK=64, XOR-swizzled LDS.

template<int COLS>
__global__ __launch_bounds__(256, 2) void k_gemm_mfma(
    const u16* __restrict__ A, const u16* __restrict__ W,
    const float* __restrict__ ss, int has_ss,
    const float* __restrict__ bias, u16* __restrict__ out,
    int nrows, int hout,
    float* __restrict__ psum, float* __restrict__ psq)
{
  constexpr int WN  = COLS/2;   // per-wave cols
  constexpr int NFR = WN/16;    // n-fragments per wave
  __shared__ u16 As[128*64];
  __shared__ u16 Bs[COLS*64];
  __shared__ float scs[256], shs[256];
  __shared__ float red[2][2][COLS];

  int tid  = threadIdx.x;
  int lane = tid & 63, wave = tid >> 6;
  int wr = wave >> 1, wc = wave & 1;
  int rbase = blockIdx.x*128;
  constexpr int cbase = 0;

  if (has_ss){ scs[tid] = ss[tid]; shs[tid] = ss[256+tid]; }
  __syncthreads();

  f32x4 acc[4][NFR];
  #pragma unroll
  for (int m=0;m<4;m++)
    #pragma unroll
    for (int n=0;n<NFR;n++)
      acc[m][n] = (f32x4){0.f,0.f,0.f,0.f};

  int arow = tid >> 1;
  int acb  = (tid & 1) * 32;
  bool avalid = (rbase + arow) < nrows;
  const u16* aptr = A + (size_t)(rbase+arow)*256 + acb;
  int brow, bcb;
  if (COLS==256)      { brow = tid;    bcb = 0; }
  else if (COLS==128) { brow = tid>>1; bcb = (tid&1)*32; }
  else                { brow = tid>>2; bcb = (tid&3)*16; }
  const u16* bptr = W + (size_t)(cbase+brow)*256 + bcb;

  for (int kt=0; kt<256; kt+=64){
    #pragma unroll
    for (int q=0;q<4;q++){
      u16x8 v = (u16x8){0,0,0,0,0,0,0,0};
      if (avalid) v = *(const u16x8*)(aptr + kt + q*8);
      if (has_ss){
        int k = acb + q*8;
        #pragma unroll
        for (int e=0;e<8;e++){
          float f = bf2f(v[e]);
          f = fmaxf(fmaf(f, scs[kt+k+e], shs[kt+k+e]), 0.f);
          v[e] = f2bf(f);
        }
      }
      int slot = ((acb>>3) + q) ^ (arow & 7);
      *(u16x8*)(As + arow*64 + slot*8) = v;
    }
    #pragma unroll
    for (int q=0;q<(COLS==256?8:COLS/32);q++){
      u16x8 v = *(const u16x8*)(bptr + kt + q*8);
      int slot = ((bcb>>3) + q) ^ (brow & 7);
      *(u16x8*)(Bs + brow*64 + slot*8) = v;
    }
    __syncthreads();

    int fr = lane & 15, g = lane >> 4;
    #pragma unroll
    for (int kk=0;kk<2;kk++){
      bf16x8 af[4], bfr[NFR];
      #pragma unroll
      for (int m=0;m<4;m++){
        int row = wr*64 + m*16 + fr;
        int slot = (kk*4 + g) ^ (row & 7);
        af[m] = *(const bf16x8*)(As + row*64 + slot*8);
      }
      #pragma unroll
      for (int n=0;n<NFR;n++){
        int row = wc*WN + n*16 + fr;
        int slot = (kk*4 + g) ^ (row & 7);
        bfr[n] = *(const bf16x8*)(Bs + row*64 + slot*8);
      }
      #pragma unroll
      for (int m=0;m<4;m++)
        #pragma unroll
        for (int n=0;n<NFR;n++)
          acc[m][n] = __builtin_amdgcn_mfma_f32_16x16x32_bf16(af[m], bfr[n], acc[m][n], 0, 0, 0);
    }
    __syncthreads();
  }

  // epilogue: bias, bf16 store, BN partial stats
  int cl = lane & 15, g = lane >> 4;
  float bv[NFR], sn[NFR], qn[NFR];
  #pragma unroll
  for (int n=0;n<NFR;n++){
    bv[n] = bias[cbase + wc*WN + n*16 + cl];
    sn[n] = 0.f; qn[n] = 0.f;
  }
  #pragma unroll
  for (int m=0;m<4;m++){
    int r0 = rbase + wr*64 + m*16 + g*4;
    #pragma unroll
    for (int n=0;n<NFR;n++){
      int c = cbase + wc*WN + n*16 + cl;
      #pragma unroll
      for (int i=0;i<4;i++){
        int r = r0 + i;
        if (r < nrows){
          float v = acc[m][n][i] + bv[n];
          out[(size_t)r*hout + c] = f2bf(v);
          sn[n] += v; qn[n] += v*v;
        }
      }
    }
  }
  #pragma unroll
  for (int n=0;n<NFR;n++){
    sn[n] += __shfl_xor(sn[n], 16, 64);
    sn[n] += __shfl_xor(sn[n], 32, 64);
    qn[n] += __shfl_xor(qn[n], 16, 64);
    qn[n] += __shfl_xor(qn[n], 32, 64);
  }
  if (lane < 16){
    #pragma unroll
    for (int n=0;n<NFR;n++){
      int cc = wc*WN + n*16 + lane;
      red[0][wr][cc] = sn[n];
      red[1][wr][cc] = qn[n];
    }
  }
  __syncthreads();
  if (tid < COLS){
    psum[(size_t)blockIdx.x*hout + cbase + tid] = red[0][0][tid] + red[0][1][tid];
    psq [(size_t)blockIdx.x*hout + cbase + tid] = red[1][0][tid] + red[1][1][tid];
  }
}

// ---- stats: partial fold + last-block final fold (deterministic: fixed order sums) ----
__global__ __launch_bounds__(256) void k_stats_partfold(
    const float* __restrict__ psum, const float* __restrict__ psq,
    int rt, int h, float* __restrict__ part, float ninv,
    const float* __restrict__ g, const float* __restrict__ b_,
    float* __restrict__ ss, int* __restrict__ counter){
  __shared__ int isLast;
  int c = threadIdx.x, b = blockIdx.x;
  int chunk = (rt + STAT_NB - 1)/STAT_NB;
  int i0 = b*chunk;
  int i1 = min(rt, i0+chunk);
  if (c < h){
    float s0=0.f,s1=0.f,s2=0.f,s3=0.f, q0=0.f,q1=0.f,q2=0.f,q3=0.f;
    int i=i0;
    for (; i+3<i1; i+=4){
      s0 += psum[(size_t)i*h+c];     q0 += psq[(size_t)i*h+c];
      s1 += psum[(size_t)(i+1)*h+c]; q1 += psq[(size_t)(i+1)*h+c];
      s2 += psum[(size_t)(i+2)*h+c]; q2 += psq[(size_t)(i+2)*h+c];
      s3 += psum[(size_t)(i+3)*h+c]; q3 += psq[(size_t)(i+3)*h+c];
    }
    for (; i<i1; ++i){ s0 += psum[(size_t)i*h+c]; q0 += psq[(size_t)i*h+c]; }
    part[((size_t)b*2  )*h + c] = (s0+s1)+(s2+s3);
    part[((size_t)b*2+1)*h + c] = (q0+q1)+(q2+q3);
  }
  __threadfence();
  if (c==0) isLast = (atomicAdd(counter,1) == gridDim.x-1);
  __syncthreads();
  if (isLast && c < h){
    float S0=0.f,S1=0.f,Q0=0.f,Q1=0.f;
    #pragma unroll 2
    for (int b2=0;b2<STAT_NB;b2+=2){
      S0 += part[((size_t)b2*2  )*h + c];
      Q0 += part[((size_t)b2*2+1)*h + c];
      S1 += part[((size_t)(b2+1)*2  )*h + c];
      Q1 += part[((size_t)(b2+1)*2+1)*h + c];
    }
    float S = S0+S1, Q = Q0+Q1;
    float m = S*ninv;
    float v = fmaxf(Q*ninv - m*m, 0.f);
    float sc = g[c] * rsqrtf(v + BN_EPS);
    ss[c]   = sc;
    ss[h+c] = b_[c] - m*sc;
  }
}

// 64 -> 14 linear (bf16 input, weights in LDS), fused BN+relu, emits stats
__global__ __launch_bounds__(256) void k_lin3(const u16* __restrict__ h3, const float* __restrict__ ss3,
     const float* __restrict__ W3, const float* __restrict__ b3,
     float* __restrict__ h4, int n, float* __restrict__ psum, float* __restrict__ psq){
  __shared__ float Ws[14*64];
  __shared__ float bs[14];
  __shared__ float sc[64], sh[64];
  __shared__ float redp[2][14][4];
  int tid=threadIdx.x;
  for (int i=tid;i<896;i+=256) Ws[i]=W3[i];
  if (tid<14) bs[tid]=b3[tid];
  if (tid<64){ sc[tid]=ss3[tid]; sh[tid]=ss3[64+tid]; }
  __syncthreads();
  int node = blockIdx.x*256 + tid;
  float o[14];
  #pragma unroll
  for (int hh=0;hh<14;hh++) o[hh]=0.f;
  if (node<n){
    const u16x8* ar = (const u16x8*)(h3 + (size_t)node*64);
    #pragma unroll
    for (int kv=0;kv<8;kv++){
      u16x8 v = ar[kv];
      #pragma unroll
      for (int j=0;j<8;j++){
        int k=kv*8+j;
        float a = fmaxf(fmaf(bf2f(v[j]), sc[k], sh[k]), 0.f);
        #pragma unroll
        for (int hh=0;hh<14;hh++) o[hh] = fmaf(a, Ws[hh*64+k], o[hh]);
      }
    }
    #pragma unroll
    for (int hh=0;hh<14;hh++){ o[hh]+=bs[hh]; h4[(size_t)node*14+hh]=o[hh]; }
  }
  int lane = tid & 63, w = tid>>6;
  #pragma unroll
  for (int hh=0;hh<14;hh++){
    float sv = (node<n)? o[hh] : 0.f;
    float qv = sv*sv;
    #pragma unroll
    for (int offs=32;offs>0;offs>>=1){
      sv += __shfl_down(sv,offs,64);
      qv += __shfl_down(qv,offs,64);
    }
    if (lane==0){ redp[0][hh][w]=sv; redp[1][hh][w]=qv; }
  }
  __syncthreads();
  if (tid<14){
    float t=redp[0][tid][0]+redp[0][tid][1]+redp[0][tid][2]+redp[0][tid][3];
    psum[(size_t)blockIdx.x*14+tid]=t;
  } else if (tid>=64 && tid<78){
    int c=tid-64;
    float t=redp[1][c][0]+redp[1][c][1]+redp[1][c][2]+redp[1][c][3];
    psq[(size_t)blockIdx.x*14+c]=t;
  }
}

// 14 -> 2 + log_softmax
__global__ void k_final(const float* __restrict__ h4, const float* __restrict__ ss4,
   const float* __restrict__ W4, const float* __restrict__ b4, float* __restrict__ out, int n){
  int node = blockIdx.x*blockDim.x+threadIdx.x;
  if (node>=n) return;
  float z0=b4[0], z1=b4[1];
  #pragma unroll
  for (int j=0;j<14;j++){
    float a = fmaxf(h4[(size_t)node*14+j]*ss4[j]+ss4[14+j], 0.f);
    z0 = fmaf(a, W4[j],    z0);
    z1 = fmaf(a, W4[14+j], z1);
  }
  float m = fmaxf(z0,z1);
  float lse = m + logf(expf(z0-m)+expf(z1-m));
  out[(size_t)node*2]   = z0-lse;
  out[(size_t)node*2+1] = z1-lse;
}

extern "C" void kernel_launch(void* const* d_in, const int* in_sizes, int n_in,
                              void* d_out, int out_size, void* d_ws, size_t ws_size,
                              hipStream_t stream){
  const float* x    = (const float*)d_in[0];
  const int*   ei   = (const int*)d_in[1];          // int64 in ref -> int32 on device per harness
  const float* Wl   = (const float*)d_in[2];
  const float* bl   = (const float*)d_in[3];
  const float* Wr   = (const float*)d_in[4];
  const float* bn_g = (const float*)d_in[5];
  const float* bn_b = (const float*)d_in[6];
  const float* W1   = (const float*)d_in[7];
  const float* b1   = (const float*)d_in[8];
  const float* W2   = (const float*)d_in[9];
  const float* b2   = (const float*)d_in[10];
  const float* W3   = (const float*)d_in[11];
  const float* b3   = (const float*)d_in[12];
  const float* W4   = (const float*)d_in[13];
  const float* b4   = (const float*)d_in[14];
  const float* g1   = (const float*)d_in[15];
  const float* bb1  = (const float*)d_in[16];
  const float* g2   = (const float*)d_in[17];
  const float* bb2  = (const float*)d_in[18];
  const float* g3   = (const float*)d_in[19];
  const float* bb3  = (const float*)d_in[20];

  const int N = in_sizes[0]/128;
  const int E = in_sizes[1]/2;
  const int NBKT = (N + 127) >> BSH;     // 128 nodes per bucket
  const int RT2 = (N+127)/128;   // 128-row GEMM tiles
  const int RT4 = (N+255)/256;   // lin3 blocks

  char* p = (char*)d_ws;
  auto alloc = [&](size_t bytes)->void*{
    void* r = (void*)p;
    p += (bytes + 255) & ~(size_t)255;
    return r;
  };
  int* deg      = (int*)alloc((size_t)N*sizeof(int));
  int* off      = (int*)alloc((size_t)N*sizeof(int));
  int* bbase    = (int*)alloc(1025*sizeof(int));
  int* flags    = (int*)alloc(16*sizeof(int));
  int* blkhist  = (int*)alloc((size_t)1024*GBIN*sizeof(int));
  int* pairs    = (int*)alloc((size_t)E*sizeof(int));
  int* eidx     = (int*)alloc((size_t)E*sizeof(int));
  u16* Acat     = (u16*)alloc((size_t)N*256*sizeof(u16));  // [agg | x] bf16; reused as h2
  u16* h1b      = (u16*)alloc((size_t)N*256*sizeof(u16));  // gemm1 out; reused as h3
  float* h4     = (float*)alloc((size_t)N*14*sizeof(float));
  u16* Wb1      = (u16*)alloc(256*256*sizeof(u16));
  u16* Wb2      = (u16*)alloc(256*256*sizeof(u16));
  u16* Wb3      = (u16*)alloc(64*256*sizeof(u16));
  float* psum   = (float*)alloc((size_t)RT2*256*sizeof(float));
  float* psq    = (float*)alloc((size_t)RT2*256*sizeof(float));
  float* part   = (float*)alloc((size_t)STAT_NB*2*256*sizeof(float));
  float* ssb    = (float*)alloc(4*512*sizeof(float));
  u16* h2b = Acat;
  u16* h3b = h1b;
  float* ss1=ssb, *ss2=ssb+512, *ss3=ssb+1024, *ss4=ssb+1536;
  const float ninv = 1.f/(float)N;

  // prep: all conversions + flag zeroing (one launch)
  k_prep<<<dim3(72+2048), dim3(256), 0, stream>>>(Wl, Wr, W1, W2, x, Wb1, Wb2, Wb3, Acat, N, flags);

  // CSR build: histogram -> scans -> partition scatter -> per-bucket sort
  k_hist<<<dim3(GBIN), dim3(256), 0, stream>>>(ei, E, NBKT, blkhist);
  k_rowscan<<<dim3((NBKT*64+255)/256), dim3(256), 0, stream>>>(blkhist, NBKT, bbase);
  k_bscan<<<dim3(1), dim3(1024), 0, stream>>>(bbase, NBKT);
  k_scatter<<<dim3(GBIN), dim3(256), 0, stream>>>(ei, E, NBKT, blkhist, bbase, pairs);
  k_bucket_csr<<<dim3(NBKT), dim3(256), 0, stream>>>(pairs, bbase, NBKT, N, deg, off, eidx);

  // mean aggregate (bf16 gather, 8-way edge-parallel) -> Acat[:,0:128]
  k_aggregate<<<dim3((N+3)/4), dim3(256), 0, stream>>>(Acat, off, deg, eidx, N);

  // GEMM1: h1 = Acat @ Wb1^T + bl   (K=256 = [agg|x] vs [Wl|Wr])
  k_gemm_mfma<256><<<dim3(RT2), dim3(256), 0, stream>>>(
      Acat, Wb1, (const float*)0, 0, bl, h1b, N, 256, psum, psq);
  k_stats_partfold<<<dim3(STAT_NB), dim3(256), 0, stream>>>(
      psum, psq, RT2, 256, part, ninv, bn_g, bn_b, ss1, flags+0);

  // GEMM2: h2 = relu(bn(h1)) @ W1^T + b1
  k_gemm_mfma<256><<<dim3(RT2), dim3(256), 0, stream>>>(
      h1b, Wb2, ss1, 1, b1, h2b, N, 256, psum, psq);
  k_stats_partfold<<<dim3(STAT_NB), dim3(256), 0, stream>>>(
      psum, psq, RT2, 256, part, ninv, g1, bb1, ss2, flags+1);

  // GEMM3: h3 = relu(bn(h2)) @ W2^T + b2  (hout=64)
  k_gemm_mfma<64><<<dim3(RT2), dim3(256), 0, stream>>>(
      h2b, Wb3, ss2, 1, b2, h3b, N, 64, psum, psq);
  k_stats_partfold<<<dim3(STAT_NB), dim3(256), 0, stream>>>(
      psum, psq, RT2, 64, part, ninv, g2, bb2, ss3, flags+2);

  // h4 = relu(bn(h3)) @ W3^T + b3   (hout=14)
  k_lin3<<<dim3(RT4), dim3(256), 0, stream>>>(h3b, ss3, W3, b3, h4, N, psum, psq);
  k_stats_partfold<<<dim3(STAT_NB), dim3(256), 0, stream>>>(
      psum, psq, RT4, 14, part, ninv, g3, bb3, ss4, flags+3);

  // out = log_softmax(relu(bn(h4)) @ W4^T + b4)
  k_final<<<dim3((N+255)/256), dim3(256), 0, stream>>>(h4, ss4, W4, b4, (float*)d_out, N);
}